// Round 10
// baseline (311.530 us; speedup 1.0000x reference)
//
#include <hip/hip_runtime.h>

typedef unsigned short u16;
typedef short s16x8 __attribute__((ext_vector_type(8)));
typedef float f32x4 __attribute__((ext_vector_type(4)));

__device__ __forceinline__ float bf2f(u16 u) {
  return __uint_as_float(((unsigned)u) << 16);
}
__device__ __forceinline__ u16 f2bf(float f) {
  unsigned x = __float_as_uint(f);
  return (u16)((x + 0x7fffu + ((x >> 16) & 1u)) >> 16);
}

// ---------------------------------------------------------------------------
// Wqkv fp32 [576][192] -> bf16. grid 54, block 256 (8 elems/thread)
// ---------------------------------------------------------------------------
__global__ __launch_bounds__(256) void wcvt_k(
    const float* __restrict__ W, u16* __restrict__ Wb)
{
  const int i = (blockIdx.x * 256 + threadIdx.x) * 8;
  const float4 f0 = *(const float4*)(W + i);
  const float4 f1 = *(const float4*)(W + i + 4);
  union { s16x8 v; u16 u[8]; } pk;
  pk.u[0]=f2bf(f0.x); pk.u[1]=f2bf(f0.y); pk.u[2]=f2bf(f0.z); pk.u[3]=f2bf(f0.w);
  pk.u[4]=f2bf(f1.x); pk.u[5]=f2bf(f1.y); pk.u[6]=f2bf(f1.z); pk.u[7]=f2bf(f1.w);
  *(s16x8*)(Wb + i) = pk.v;
}

// ---------------------------------------------------------------------------
// Fused transpose+GEMM for qkv: qkv[b][oc][p] = sum_c Wb[oc][c] * x[b][c][p].
// p-tile 64: xs = 25.6KB -> ~6 blocks/CU (high occupancy). Lean registers
// (~60 VGPR): W fragments read from global (L1/L2-hot) in the kq loop.
// Staging: c-pair dword writes, row rotated by (j+quad)&3 -> ~4-way worst
// bank conflicts (was 16-way).  xs rows 200 u16 -> even bank spread on
// ds_read_b128 (bank = 4*(l15+l4) mod 32, 8 dwords/bank).
// grid (256, 8), block 256 (4 waves: 2 oc-halves x 2 p-halves)
// ---------------------------------------------------------------------------
__global__ __launch_bounds__(256) void qkv_fused(
    const float* __restrict__ x, const u16* __restrict__ Wb,
    u16* __restrict__ qkv)
{
  __shared__ u16 xs[64*200];
  const int t = threadIdx.x, wave = t >> 6, lane = t & 63;
  const int l15 = lane & 15, l4 = lane >> 4;
  const int p0 = blockIdx.x * 64, b = blockIdx.y;

  // stage x[c][p-tile] -> xs[p][c] (fp32 -> bf16), c-pair packed dwords
  const float* const xb = x + (long)b*192*16384 + p0;
  #pragma unroll
  for (int i = 0; i < 6; i++) {
    const int idx = t + i*256;          // (c-pair, p-quad)
    const int cp = idx >> 4, quad = idx & 15;
    const int c = cp*2, p4 = quad*4;
    const float4 f0 = *(const float4*)(xb + (long)c*16384 + p4);
    const float4 f1 = *(const float4*)(xb + (long)(c+1)*16384 + p4);
    const float a0[4] = {f0.x, f0.y, f0.z, f0.w};
    const float a1[4] = {f1.x, f1.y, f1.z, f1.w};
    #pragma unroll
    for (int j = 0; j < 4; j++) {
      const int jj = (j + quad) & 3;    // rotation: spreads banks across lanes
      const unsigned v = (unsigned)f2bf(a0[jj]) | ((unsigned)f2bf(a1[jj]) << 16);
      *(unsigned*)(&xs[(p4 + jj)*200 + c]) = v;
    }
  }
  __syncthreads();

  const int ocH = (wave >> 1) * 288, pH = (wave & 1) * 32;
  u16* const qb = qkv + (long)b*576*16384 + p0 + pH;

  for (int ot = 0; ot < 9; ot++) {
    const int oc0 = ocH + ot*32;
    f32x4 acc[2][2];
    #pragma unroll
    for (int mi = 0; mi < 2; mi++)
      #pragma unroll
      for (int ni = 0; ni < 2; ni++) acc[mi][ni] = (f32x4){0.f,0.f,0.f,0.f};

    #pragma unroll
    for (int kq = 0; kq < 6; kq++) {
      s16x8 wf[2], bx[2];
      #pragma unroll
      for (int ni = 0; ni < 2; ni++)
        wf[ni] = *(const s16x8*)(Wb + (long)(oc0 + ni*16 + l15)*192 + kq*32 + l4*8);
      #pragma unroll
      for (int mi = 0; mi < 2; mi++)
        bx[mi] = *(const s16x8*)(xs + (pH + mi*16 + l15)*200 + kq*32 + l4*8);
      #pragma unroll
      for (int mi = 0; mi < 2; mi++)
        #pragma unroll
        for (int ni = 0; ni < 2; ni++)
          acc[mi][ni] = __builtin_amdgcn_mfma_f32_16x16x32_bf16(
              wf[ni], bx[mi], acc[mi][ni], 0, 0, 0);
    }

    #pragma unroll
    for (int mi = 0; mi < 2; mi++) {
      const int p = mi*16 + l15;
      #pragma unroll
      for (int ni = 0; ni < 2; ni++) {
        #pragma unroll
        for (int j = 0; j < 4; j++) {
          const int row = oc0 + ni*16 + l4*4 + j;
          qb[(long)row*16384 + p] = f2bf(acc[mi][ni][j]);
        }
      }
    }
  }
}

// ---------------------------------------------------------------------------
// Fused transpose+GEMM for proj: out[b][o][p] = sum_g M2[b][o][g] * v[g][p].
// Same geometry as qkv_fused (p-tile 64, lean regs, rotated staging).
// grid (256, 8), block 256
// ---------------------------------------------------------------------------
__global__ __launch_bounds__(256) void proj_fused(
    const u16* __restrict__ qkv, const u16* __restrict__ M2,
    float* __restrict__ outp)
{
  __shared__ u16 vs[64*200];
  const int t = threadIdx.x, wave = t >> 6, lane = t & 63;
  const int l15 = lane & 15, l4 = lane >> 4;
  const int p0 = blockIdx.x * 64, b = blockIdx.y;

  // stage v[g][p-tile] -> vs[p][g] (bf16), rows rotated by (j+oct)&7
  const u16* const vb = qkv + ((long)b*576 + 384)*16384 + p0;
  #pragma unroll
  for (int i = 0; i < 6; i++) {
    const int idx = t + i*256;          // (g, p-oct)
    const int g = idx >> 3, oct = idx & 7;
    union { s16x8 v; u16 u[8]; } ld;
    ld.v = *(const s16x8*)(vb + (long)g*16384 + oct*8);
    #pragma unroll
    for (int j = 0; j < 8; j++) {
      const int jj = (j + oct) & 7;
      vs[(oct*8 + jj)*200 + g] = ld.u[jj];
    }
  }
  __syncthreads();

  const int ocH = (wave >> 1) * 96, pH = (wave & 1) * 32;
  const u16* const Mb = M2 + (long)b * 36864;
  float* const ob = outp + (long)b*192*16384 + p0 + pH;

  for (int ot = 0; ot < 3; ot++) {
    const int oc0 = ocH + ot*32;
    f32x4 acc[2][2];
    #pragma unroll
    for (int mi = 0; mi < 2; mi++)
      #pragma unroll
      for (int ni = 0; ni < 2; ni++) acc[mi][ni] = (f32x4){0.f,0.f,0.f,0.f};

    #pragma unroll
    for (int kq = 0; kq < 6; kq++) {
      s16x8 wf[2], bx[2];
      #pragma unroll
      for (int ni = 0; ni < 2; ni++)
        wf[ni] = *(const s16x8*)(Mb + (long)(oc0 + ni*16 + l15)*192 + kq*32 + l4*8);
      #pragma unroll
      for (int mi = 0; mi < 2; mi++)
        bx[mi] = *(const s16x8*)(vs + (pH + mi*16 + l15)*200 + kq*32 + l4*8);
      #pragma unroll
      for (int mi = 0; mi < 2; mi++)
        #pragma unroll
        for (int ni = 0; ni < 2; ni++)
          acc[mi][ni] = __builtin_amdgcn_mfma_f32_16x16x32_bf16(
              wf[ni], bx[mi], acc[mi][ni], 0, 0, 0);
    }

    #pragma unroll
    for (int mi = 0; mi < 2; mi++) {
      const int p = mi*16 + l15;
      #pragma unroll
      for (int ni = 0; ni < 2; ni++) {
        #pragma unroll
        for (int j = 0; j < 4; j++) {
          const int row = oc0 + ni*16 + l4*4 + j;
          ob[(long)row*16384 + p] = acc[mi][ni][j];
        }
      }
    }
  }
}

// ---------------------------------------------------------------------------
// Depthwise 3x3 conv, padding 1, IN-PLACE on qkv (bf16). One block per
// (channel, batch); plane staged in LDS [130][132]; 16B lane-contiguous I/O.
// grid (576, 8), block 256
// ---------------------------------------------------------------------------
__global__ __launch_bounds__(256) void dwconv_k(
    u16* __restrict__ qkv, const float* __restrict__ Wdw)
{
  __shared__ u16 lds[130*132];
  const int ch = blockIdx.x, b = blockIdx.y;
  u16* const base = qkv + ((long)b * 576 + ch) * 16384;
  const int t = threadIdx.x;

  {
    uint4* z = (uint4*)lds;
    #pragma unroll
    for (int i = 0; i < 9; i++) {
      const int idx = t + i*256;
      if (idx < 2145) z[idx] = (uint4){0,0,0,0};
    }
  }
  float w[9];
  #pragma unroll
  for (int i = 0; i < 9; i++) w[i] = Wdw[ch*9 + i];
  __syncthreads();

  #pragma unroll
  for (int i = 0; i < 8; i++) {
    const int p = t + i*256;
    const int y = p >> 4, x = (p & 15) * 8;
    union { uint4 v; u16 u[8]; } ld;
    ld.v = *(const uint4*)(base + y*128 + x);
    u16* d = &lds[(y+1)*132 + x + 1];
    #pragma unroll
    for (int kk = 0; kk < 8; kk++) d[kk] = ld.u[kk];
  }
  __syncthreads();

  #pragma unroll
  for (int i = 0; i < 8; i++) {
    const int p = t + i*256;
    const int y = p >> 4, x = (p & 15) * 8;
    float r[3][10];
    #pragma unroll
    for (int dy = 0; dy < 3; dy++)
      #pragma unroll
      for (int j = 0; j < 10; j++)
        r[dy][j] = bf2f(lds[(y+dy)*132 + x + j]);
    float acc[8];
    #pragma unroll
    for (int xx = 0; xx < 8; xx++)
      acc[xx] = w[0]*r[0][xx] + w[1]*r[0][xx+1] + w[2]*r[0][xx+2]
              + w[3]*r[1][xx] + w[4]*r[1][xx+1] + w[5]*r[1][xx+2]
              + w[6]*r[2][xx] + w[7]*r[2][xx+1] + w[8]*r[2][xx+2];
    union { uint4 v; u16 u[8]; } st;
    #pragma unroll
    for (int xx = 0; xx < 8; xx++) st.u[xx] = f2bf(acc[xx]);
    *(uint4*)(base + y*128 + x) = st.v;
  }
}

// ---------------------------------------------------------------------------
// Gram: per (b,h) 48x48 self-product of rows U=[q*f ; k*f] over k-chunk 2048.
// Feature multiply fused into staging (f read once; q,k rows share one load).
// grid (8 kc, 64 bh), block 256 (4 waves)
// ---------------------------------------------------------------------------
__global__ __launch_bounds__(256) void gram_k(
    const u16* __restrict__ qkv, const float* __restrict__ feature,
    float* __restrict__ Gp)
{
  __shared__ u16 us[48*128];
  __shared__ float red[4*2304];
  const int kc = blockIdx.x, bh = blockIdx.y;
  const int b = bh >> 3, h = bh & 7;
  const int t = threadIdx.x, wave = t >> 6, lane = t & 63;
  const int l15 = lane & 15, l4 = lane >> 4;
  const u16* const qbase = qkv + ((long)b*576 + h*24) * 16384;
  const u16* const kbase = qkv + ((long)b*576 + 192 + h*24) * 16384;
  const float* const fbase = feature + ((long)b*192 + h*24) * 16384;
  char* const usb = (char*)us;

  f32x4 acc[3][3];
  #pragma unroll
  for (int i = 0; i < 3; i++)
    #pragma unroll
    for (int j = 0; j < 3; j++) acc[i][j] = (f32x4){0.f, 0.f, 0.f, 0.f};

  for (int step = 0; step < 16; step++) {
    const int k0 = kc*2048 + step*128;
    #pragma unroll
    for (int i = 0; i < 3; i++) {
      const int idx = t + i*256;        // 0..767: 24 c-rows x 32 4px-groups
      const int r = idx >> 5, d4 = idx & 31;
      const long po = (long)r*16384 + k0 + d4*4;
      const float4 f4 = *(const float4*)(fbase + po);
      union { uint2 v; u16 u[4]; } uq, uk, oq, ok;
      uq.v = *(const uint2*)(qbase + po);
      uk.v = *(const uint2*)(kbase + po);
      const float fv[4] = {f4.x, f4.y, f4.z, f4.w};
      #pragma unroll
      for (int j = 0; j < 4; j++) {
        oq.u[j] = f2bf(bf2f(uq.u[j]) * fv[j]);
        ok.u[j] = f2bf(bf2f(uk.u[j]) * fv[j]);
      }
      const int col = d4*4;
      const int sub = ((col&7)<<1);
      const int r2 = r + 24;
      *(uint2*)(usb + r *256 + (((col>>3) ^ (r &7)) << 4) + sub) = oq.v;
      *(uint2*)(usb + r2*256 + (((col>>3) ^ (r2&7)) << 4) + sub) = ok.v;
    }
    __syncthreads();
    {
      const int kb = wave*4 + l4;
      s16x8 fr[3];
      #pragma unroll
      for (int g = 0; g < 3; g++) {
        const int row = g*16 + l15;
        fr[g] = *(const s16x8*)(usb + row*256 + ((kb ^ (row&7)) << 4));
      }
      #pragma unroll
      for (int gm = 0; gm < 3; gm++)
        #pragma unroll
        for (int gn = 0; gn < 3; gn++)
          acc[gm][gn] = __builtin_amdgcn_mfma_f32_16x16x32_bf16(fr[gm], fr[gn], acc[gm][gn], 0, 0, 0);
    }
    __syncthreads();
  }
  #pragma unroll
  for (int gm = 0; gm < 3; gm++)
    #pragma unroll
    for (int gn = 0; gn < 3; gn++)
      #pragma unroll
      for (int j = 0; j < 4; j++) {
        const int r = gm*16 + l4*4 + j, s = gn*16 + l15;
        red[wave*2304 + r*48 + s] = acc[gm][gn][j];
      }
  __syncthreads();
  for (int idx = t; idx < 2304; idx += 256) {
    const float sum = red[idx] + red[2304+idx] + red[4608+idx] + red[6912+idx];
    Gp[((long)bh*8 + kc)*2304 + idx] = sum;
  }
}

// ---------------------------------------------------------------------------
// Finalize attention: reduce Gram over kc, normalize, temperature, softmax.
// grid 64 (bh), block 256
// ---------------------------------------------------------------------------
__global__ __launch_bounds__(256) void attnfin_k(
    const float* __restrict__ Gp, const float* __restrict__ temperature,
    float* __restrict__ attn)
{
  __shared__ float cross[576];
  __shared__ float qn[24], kn[24];
  const int bh = blockIdx.x, h = bh & 7;
  const int t = threadIdx.x;
  const float* const g = Gp + (long)bh * 8 * 2304;
  for (int idx = t; idx < 624; idx += 256) {
    float s = 0.f;
    if (idx < 576) {
      const int c = idx / 24, d = idx - c * 24;
      #pragma unroll
      for (int kc = 0; kc < 8; kc++) s += g[kc*2304 + c*48 + 24 + d];
      cross[idx] = s;
    } else {
      const int r = idx - 576;
      #pragma unroll
      for (int kc = 0; kc < 8; kc++) s += g[kc*2304 + r*48 + r];
      const float nv = fmaxf(sqrtf(s), 1e-12f);
      if (r < 24) qn[r] = nv; else kn[r-24] = nv;
    }
  }
  __syncthreads();
  if (t < 24) {
    const float tmp = temperature[h];
    const float qi = 1.f / qn[t];
    float vals[24];
    float m = -1e30f;
    #pragma unroll
    for (int d = 0; d < 24; d++) {
      const float v = cross[t*24 + d] * qi / kn[d] * tmp;
      vals[d] = v; m = fmaxf(m, v);
    }
    float s = 0.f;
    #pragma unroll
    for (int d = 0; d < 24; d++) { vals[d] = __expf(vals[d] - m); s += vals[d]; }
    const float inv = 1.f / s;
    #pragma unroll
    for (int d = 0; d < 24; d++) attn[(long)bh*576 + t*24 + d] = vals[d] * inv;
  }
}

// ---------------------------------------------------------------------------
// M2[b][o][g] = sum_c Wproj[o][h(g)*24+c] * attn[b][h(g)][c][d(g)]  (bf16 out)
// grid 1152, block 256
// ---------------------------------------------------------------------------
__global__ __launch_bounds__(256) void m2_k(
    const float* __restrict__ attn, const float* __restrict__ Wp,
    u16* __restrict__ M2)
{
  const int gid = blockIdx.x * 256 + threadIdx.x;
  const int g = gid % 192;
  const int rem = gid / 192;
  const int o = rem % 192;
  const int b = rem / 192;
  const int h = g / 24, d = g - h*24;
  const float* a = attn + ((long)(b*8 + h) * 24) * 24 + d;
  const float* w = Wp + (long)o * 192 + h * 24;
  float s = 0.f;
  #pragma unroll
  for (int c = 0; c < 24; c++) s += w[c] * a[c*24];
  M2[gid] = f2bf(s);
}

// ---------------------------------------------------------------------------
extern "C" void kernel_launch(void* const* d_in, const int* in_sizes, int n_in,
                              void* d_out, int out_size, void* d_ws, size_t ws_size,
                              hipStream_t stream) {
  const float* x    = (const float*)d_in[0];
  const float* fe   = (const float*)d_in[1];
  const float* Wqkv = (const float*)d_in[2];
  const float* Wdw  = (const float*)d_in[3];
  const float* Wpr  = (const float*)d_in[4];
  const float* temp = (const float*)d_in[5];

  char* ws = (char*)d_ws;
  u16*   qkv = (u16*)ws;                          // 150,994,944 B [b][576][16384]
  float* Gp  = (float*)(ws + 150994944L);         // 4,718,592 B   [64][8][2304]
  float* attn= (float*)(ws + 155713536L);         // 147,456 B     [64][24][24]
  u16*   M2  = (u16*)(ws + 155860992L);           // 589,824 B     [b][192][192]
  u16*   Wb  = (u16*)(ws + 156450816L);           // 221,184 B     Wqkv bf16

  wcvt_k<<<54, 256, 0, stream>>>(Wqkv, Wb);
  qkv_fused<<<dim3(256,8), 256, 0, stream>>>(x, Wb, qkv);
  dwconv_k<<<dim3(576,8), 256, 0, stream>>>(qkv, Wdw);
  gram_k<<<dim3(8,64), 256, 0, stream>>>(qkv, fe, Gp);
  attnfin_k<<<64, 256, 0, stream>>>(Gp, temp, attn);
  m2_k<<<1152, 256, 0, stream>>>(attn, Wpr, M2);
  proj_fused<<<dim3(256,8), 256, 0, stream>>>(qkv, M2, (float*)d_out);
}